// Round 1
// baseline (1395.117 us; speedup 1.0000x reference)
//
#include <hip/hip_runtime.h>

// Problem constants (fixed by the reference)
#define NP 50000
#define NG 20000
#define NE 640000
#define PD 64
#define GD 32
#define HD 128
#define OD 8
#define RD 8   // rows per block

// ---------------------------------------------------------------------------
// Gene MLP: g = relu(xg @ Wg1 + bg1) @ Wg2 + bg2      [NG, HD]
// 128 threads = one output channel each; RD rows per block.
// xg read with block-uniform indices (scalar-load friendly); h1 via LDS.
// ---------------------------------------------------------------------------
__global__ __launch_bounds__(128) void gene_mlp_kernel(
    const float* __restrict__ xg,
    const float* __restrict__ Wg1, const float* __restrict__ bg1,
    const float* __restrict__ Wg2, const float* __restrict__ bg2,
    float* __restrict__ g)
{
    __shared__ __align__(16) float A[RD * HD];
    const int j = threadIdx.x;
    const int row0 = blockIdx.x * RD;

    float acc[RD];
    // layer 1: relu(xg @ Wg1 + bg1) -> A (LDS)
    {
        const float b = bg1[j];
#pragma unroll
        for (int r = 0; r < RD; ++r) acc[r] = b;
        for (int k = 0; k < GD; k += 4) {
            const float w0 = Wg1[(k + 0) * HD + j];
            const float w1 = Wg1[(k + 1) * HD + j];
            const float w2 = Wg1[(k + 2) * HD + j];
            const float w3 = Wg1[(k + 3) * HD + j];
#pragma unroll
            for (int r = 0; r < RD; ++r) {
                const float* xr = xg + (size_t)(row0 + r) * GD + k;
                acc[r] = fmaf(xr[0], w0, acc[r]);
                acc[r] = fmaf(xr[1], w1, acc[r]);
                acc[r] = fmaf(xr[2], w2, acc[r]);
                acc[r] = fmaf(xr[3], w3, acc[r]);
            }
        }
#pragma unroll
        for (int r = 0; r < RD; ++r) A[r * HD + j] = fmaxf(acc[r], 0.f);
        __syncthreads();
    }
    // layer 2: A @ Wg2 + bg2 (no relu) -> g (global)
    {
        const float b = bg2[j];
#pragma unroll
        for (int r = 0; r < RD; ++r) acc[r] = b;
        for (int k = 0; k < HD; k += 4) {
            const float w0 = Wg2[(k + 0) * HD + j];
            const float w1 = Wg2[(k + 1) * HD + j];
            const float w2 = Wg2[(k + 2) * HD + j];
            const float w3 = Wg2[(k + 3) * HD + j];
#pragma unroll
            for (int r = 0; r < RD; ++r) {
                const float4 a4 = *(const float4*)&A[r * HD + k];
                acc[r] = fmaf(a4.x, w0, acc[r]);
                acc[r] = fmaf(a4.y, w1, acc[r]);
                acc[r] = fmaf(a4.z, w2, acc[r]);
                acc[r] = fmaf(a4.w, w3, acc[r]);
            }
        }
#pragma unroll
        for (int r = 0; r < RD; ++r) g[(size_t)(row0 + r) * HD + j] = acc[r];
    }
}

// ---------------------------------------------------------------------------
// Edge scatter: agg[dst] += g[src]  (segment_sum). 32 lanes per edge,
// float4 gather from g, 4 fp32 atomics per lane.
// ---------------------------------------------------------------------------
__global__ __launch_bounds__(256) void scatter_add_kernel(
    const int* __restrict__ ei,   // [2, NE]
    const float* __restrict__ g,  // [NG, HD]
    float* __restrict__ agg)      // [NP, HD]
{
    const int t = blockIdx.x * 256 + threadIdx.x;
    const int e = t >> 5;
    const int c = (t & 31) << 2;
    if (e < NE) {
        const int s = ei[e];
        const int d = ei[NE + e];
        const float4 v = *(const float4*)&g[(size_t)s * HD + c];
        float* ap = &agg[(size_t)d * HD + c];
        atomicAdd(ap + 0, v.x);
        atomicAdd(ap + 1, v.y);
        atomicAdd(ap + 2, v.z);
        atomicAdd(ap + 3, v.w);
    }
}

// ---------------------------------------------------------------------------
// Fused patient pipeline:
//   p   = relu(xp @ Wp1 + bp1) @ Wp2 + bp2
//   h1  = relu(agg @ W1l + b1l + p  @ W1r)
//   h2  = relu(agg @ W2l + b2l + h1 @ W2r)
//   out = h2 @ Wfc + bfc
// 128 threads (one channel each), RD rows/block. agg & xp read with
// block-uniform indices (global, scalar-load friendly); intermediates in LDS.
// ---------------------------------------------------------------------------
__global__ __launch_bounds__(128) void patient_fused_kernel(
    const float* __restrict__ xp,   // [NP, PD]
    const float* __restrict__ agg,  // [NP, HD]
    const float* __restrict__ Wp1, const float* __restrict__ bp1,
    const float* __restrict__ Wp2, const float* __restrict__ bp2,
    const float* __restrict__ W1l, const float* __restrict__ b1l,
    const float* __restrict__ W1r,
    const float* __restrict__ W2l, const float* __restrict__ b2l,
    const float* __restrict__ W2r,
    const float* __restrict__ Wfc, const float* __restrict__ bfc,
    float* __restrict__ out)        // [NP, OD]
{
    __shared__ __align__(16) float A[RD * HD];
    __shared__ __align__(16) float B[RD * HD];
    const int j = threadIdx.x;
    const int row0 = blockIdx.x * RD;

    float acc[RD];

    // ---- patient MLP layer 1: relu(xp @ Wp1 + bp1) -> A
    {
        const float b = bp1[j];
#pragma unroll
        for (int r = 0; r < RD; ++r) acc[r] = b;
        for (int k = 0; k < PD; k += 4) {
            const float w0 = Wp1[(k + 0) * HD + j];
            const float w1 = Wp1[(k + 1) * HD + j];
            const float w2 = Wp1[(k + 2) * HD + j];
            const float w3 = Wp1[(k + 3) * HD + j];
#pragma unroll
            for (int r = 0; r < RD; ++r) {
                const float* xr = xp + (size_t)(row0 + r) * PD + k;
                acc[r] = fmaf(xr[0], w0, acc[r]);
                acc[r] = fmaf(xr[1], w1, acc[r]);
                acc[r] = fmaf(xr[2], w2, acc[r]);
                acc[r] = fmaf(xr[3], w3, acc[r]);
            }
        }
#pragma unroll
        for (int r = 0; r < RD; ++r) A[r * HD + j] = fmaxf(acc[r], 0.f);
        __syncthreads();
    }

    // ---- patient MLP layer 2: A @ Wp2 + bp2 (no relu) -> B
    {
        const float b = bp2[j];
#pragma unroll
        for (int r = 0; r < RD; ++r) acc[r] = b;
        for (int k = 0; k < HD; k += 4) {
            const float w0 = Wp2[(k + 0) * HD + j];
            const float w1 = Wp2[(k + 1) * HD + j];
            const float w2 = Wp2[(k + 2) * HD + j];
            const float w3 = Wp2[(k + 3) * HD + j];
#pragma unroll
            for (int r = 0; r < RD; ++r) {
                const float4 a4 = *(const float4*)&A[r * HD + k];
                acc[r] = fmaf(a4.x, w0, acc[r]);
                acc[r] = fmaf(a4.y, w1, acc[r]);
                acc[r] = fmaf(a4.z, w2, acc[r]);
                acc[r] = fmaf(a4.w, w3, acc[r]);
            }
        }
        __syncthreads();  // everyone done reading A
#pragma unroll
        for (int r = 0; r < RD; ++r) B[r * HD + j] = acc[r];
        __syncthreads();
    }

    // ---- SAGE layer 1: relu(agg @ W1l + b1l + B @ W1r) -> A
    {
        const float b = b1l[j];
#pragma unroll
        for (int r = 0; r < RD; ++r) acc[r] = b;
        for (int k = 0; k < HD; k += 4) {
            const float wl0 = W1l[(k + 0) * HD + j];
            const float wl1 = W1l[(k + 1) * HD + j];
            const float wl2 = W1l[(k + 2) * HD + j];
            const float wl3 = W1l[(k + 3) * HD + j];
            const float wr0 = W1r[(k + 0) * HD + j];
            const float wr1 = W1r[(k + 1) * HD + j];
            const float wr2 = W1r[(k + 2) * HD + j];
            const float wr3 = W1r[(k + 3) * HD + j];
#pragma unroll
            for (int r = 0; r < RD; ++r) {
                const float* ar = agg + (size_t)(row0 + r) * HD + k;
                const float4 p4 = *(const float4*)&B[r * HD + k];
                acc[r] = fmaf(ar[0], wl0, acc[r]);
                acc[r] = fmaf(p4.x, wr0, acc[r]);
                acc[r] = fmaf(ar[1], wl1, acc[r]);
                acc[r] = fmaf(p4.y, wr1, acc[r]);
                acc[r] = fmaf(ar[2], wl2, acc[r]);
                acc[r] = fmaf(p4.z, wr2, acc[r]);
                acc[r] = fmaf(ar[3], wl3, acc[r]);
                acc[r] = fmaf(p4.w, wr3, acc[r]);
            }
        }
        __syncthreads();  // everyone done reading B
#pragma unroll
        for (int r = 0; r < RD; ++r) A[r * HD + j] = fmaxf(acc[r], 0.f);
        __syncthreads();
    }

    // ---- SAGE layer 2: relu(agg @ W2l + b2l + A @ W2r) -> B
    {
        const float b = b2l[j];
#pragma unroll
        for (int r = 0; r < RD; ++r) acc[r] = b;
        for (int k = 0; k < HD; k += 4) {
            const float wl0 = W2l[(k + 0) * HD + j];
            const float wl1 = W2l[(k + 1) * HD + j];
            const float wl2 = W2l[(k + 2) * HD + j];
            const float wl3 = W2l[(k + 3) * HD + j];
            const float wr0 = W2r[(k + 0) * HD + j];
            const float wr1 = W2r[(k + 1) * HD + j];
            const float wr2 = W2r[(k + 2) * HD + j];
            const float wr3 = W2r[(k + 3) * HD + j];
#pragma unroll
            for (int r = 0; r < RD; ++r) {
                const float* ar = agg + (size_t)(row0 + r) * HD + k;
                const float4 h4 = *(const float4*)&A[r * HD + k];
                acc[r] = fmaf(ar[0], wl0, acc[r]);
                acc[r] = fmaf(h4.x, wr0, acc[r]);
                acc[r] = fmaf(ar[1], wl1, acc[r]);
                acc[r] = fmaf(h4.y, wr1, acc[r]);
                acc[r] = fmaf(ar[2], wl2, acc[r]);
                acc[r] = fmaf(h4.z, wr2, acc[r]);
                acc[r] = fmaf(ar[3], wl3, acc[r]);
                acc[r] = fmaf(h4.w, wr3, acc[r]);
            }
        }
        __syncthreads();  // everyone done reading A
#pragma unroll
        for (int r = 0; r < RD; ++r) B[r * HD + j] = fmaxf(acc[r], 0.f);
        __syncthreads();
    }

    // ---- fc: out = B @ Wfc + bfc  (threads 0..RD*OD-1, one (row, out) each)
    if (j < RD * OD) {
        const int r = j >> 3;
        const int o = j & 7;
        float s = bfc[o];
        for (int k = 0; k < HD; k += 4) {
            const float4 h4 = *(const float4*)&B[r * HD + k];
            s = fmaf(h4.x, Wfc[(k + 0) * OD + o], s);
            s = fmaf(h4.y, Wfc[(k + 1) * OD + o], s);
            s = fmaf(h4.z, Wfc[(k + 2) * OD + o], s);
            s = fmaf(h4.w, Wfc[(k + 3) * OD + o], s);
        }
        out[(size_t)(row0 + r) * OD + o] = s;
    }
}

// ---------------------------------------------------------------------------
extern "C" void kernel_launch(void* const* d_in, const int* in_sizes, int n_in,
                              void* d_out, int out_size, void* d_ws, size_t ws_size,
                              hipStream_t stream)
{
    const float* xp  = (const float*)d_in[0];
    const float* xg  = (const float*)d_in[1];
    const int*   ei  = (const int*)d_in[2];
    const float* Wp1 = (const float*)d_in[3];
    const float* bp1 = (const float*)d_in[4];
    const float* Wp2 = (const float*)d_in[5];
    const float* bp2 = (const float*)d_in[6];
    const float* Wg1 = (const float*)d_in[7];
    const float* bg1 = (const float*)d_in[8];
    const float* Wg2 = (const float*)d_in[9];
    const float* bg2 = (const float*)d_in[10];
    const float* W1l = (const float*)d_in[11];
    const float* b1l = (const float*)d_in[12];
    const float* W1r = (const float*)d_in[13];
    const float* W2l = (const float*)d_in[14];
    const float* b2l = (const float*)d_in[15];
    const float* W2r = (const float*)d_in[16];
    const float* Wfc = (const float*)d_in[17];
    const float* bfc = (const float*)d_in[18];
    float* out = (float*)d_out;

    // workspace layout: g [NG*HD] fp32 | agg [NP*HD] fp32
    float* g   = (float*)d_ws;
    float* agg = g + (size_t)NG * HD;

    // 1) gene MLP
    gene_mlp_kernel<<<NG / RD, 128, 0, stream>>>(xg, Wg1, bg1, Wg2, bg2, g);

    // 2) zero agg (ws is poisoned 0xAA before every call)
    hipMemsetAsync(agg, 0, (size_t)NP * HD * sizeof(float), stream);

    // 3) edge scatter (segment_sum)
    scatter_add_kernel<<<(NE * 32) / 256, 256, 0, stream>>>(ei, g, agg);

    // 4) fused patient MLP + SAGE1 + SAGE2 + fc
    patient_fused_kernel<<<NP / RD, 128, 0, stream>>>(
        xp, agg, Wp1, bp1, Wp2, bp2, W1l, b1l, W1r, W2l, b2l, W2r, Wfc, bfc, out);
}

// Round 2
// 425.900 us; speedup vs baseline: 3.2757x; 3.2757x over previous
//
#include <hip/hip_runtime.h>

// Problem constants (fixed by the reference)
#define NP 50000
#define NG 20000
#define NE 640000
#define PD 64
#define GD 32
#define HD 128
#define OD 8
#define RD 8    // rows per block (MLP kernels)

#define SCAN_CHUNK 1024
#define SCAN_NB ((NP + SCAN_CHUNK - 1) / SCAN_CHUNK)   // 49

// ---------------------------------------------------------------------------
// Gene MLP: g = relu(xg @ Wg1 + bg1) @ Wg2 + bg2      [NG, HD]
// ---------------------------------------------------------------------------
__global__ __launch_bounds__(128) void gene_mlp_kernel(
    const float* __restrict__ xg,
    const float* __restrict__ Wg1, const float* __restrict__ bg1,
    const float* __restrict__ Wg2, const float* __restrict__ bg2,
    float* __restrict__ g)
{
    __shared__ __align__(16) float A[RD * HD];
    const int j = threadIdx.x;
    const int row0 = blockIdx.x * RD;

    float acc[RD];
    // layer 1: relu(xg @ Wg1 + bg1) -> A (LDS)
    {
        const float b = bg1[j];
#pragma unroll
        for (int r = 0; r < RD; ++r) acc[r] = b;
        for (int k = 0; k < GD; k += 4) {
            const float w0 = Wg1[(k + 0) * HD + j];
            const float w1 = Wg1[(k + 1) * HD + j];
            const float w2 = Wg1[(k + 2) * HD + j];
            const float w3 = Wg1[(k + 3) * HD + j];
#pragma unroll
            for (int r = 0; r < RD; ++r) {
                const float* xr = xg + (size_t)(row0 + r) * GD + k;
                acc[r] = fmaf(xr[0], w0, acc[r]);
                acc[r] = fmaf(xr[1], w1, acc[r]);
                acc[r] = fmaf(xr[2], w2, acc[r]);
                acc[r] = fmaf(xr[3], w3, acc[r]);
            }
        }
#pragma unroll
        for (int r = 0; r < RD; ++r) A[r * HD + j] = fmaxf(acc[r], 0.f);
        __syncthreads();
    }
    // layer 2: A @ Wg2 + bg2 (no relu) -> g (global)
    {
        const float b = bg2[j];
#pragma unroll
        for (int r = 0; r < RD; ++r) acc[r] = b;
        for (int k = 0; k < HD; k += 4) {
            const float w0 = Wg2[(k + 0) * HD + j];
            const float w1 = Wg2[(k + 1) * HD + j];
            const float w2 = Wg2[(k + 2) * HD + j];
            const float w3 = Wg2[(k + 3) * HD + j];
#pragma unroll
            for (int r = 0; r < RD; ++r) {
                const float4 a4 = *(const float4*)&A[r * HD + k];
                acc[r] = fmaf(a4.x, w0, acc[r]);
                acc[r] = fmaf(a4.y, w1, acc[r]);
                acc[r] = fmaf(a4.z, w2, acc[r]);
                acc[r] = fmaf(a4.w, w3, acc[r]);
            }
        }
#pragma unroll
        for (int r = 0; r < RD; ++r) g[(size_t)(row0 + r) * HD + j] = acc[r];
    }
}

// ---------------------------------------------------------------------------
// CSR build: histogram of dst
// ---------------------------------------------------------------------------
__global__ __launch_bounds__(256) void hist_kernel(
    const int* __restrict__ ei, int* __restrict__ counts)
{
    const int e = blockIdx.x * 256 + threadIdx.x;
    if (e < NE) atomicAdd(&counts[ei[NE + e]], 1);
}

// per-chunk sums (chunk = 1024 counts)
__global__ __launch_bounds__(256) void blocksum_kernel(
    const int* __restrict__ counts, int* __restrict__ bsum)
{
    __shared__ int sdata[256];
    const int t = threadIdx.x;
    const int base = blockIdx.x * SCAN_CHUNK;
    int s = 0;
#pragma unroll
    for (int k = 0; k < 4; ++k) {
        const int i = base + t * 4 + k;
        if (i < NP) s += counts[i];
    }
    sdata[t] = s;
    __syncthreads();
    for (int off = 128; off > 0; off >>= 1) {
        if (t < off) sdata[t] += sdata[t + off];
        __syncthreads();
    }
    if (t == 0) bsum[blockIdx.x] = sdata[0];
}

// serial exclusive scan of the (49) chunk sums; also writes offsets[NP]
__global__ void scanbsums_kernel(int* __restrict__ bsum, int* __restrict__ offsets)
{
    if (threadIdx.x == 0 && blockIdx.x == 0) {
        int run = 0;
        for (int b = 0; b < SCAN_NB; ++b) {
            const int v = bsum[b];
            bsum[b] = run;
            run += v;
        }
        offsets[NP] = run;  // == NE
    }
}

// per-chunk exclusive scan -> offsets (and cursor copy for the fill pass)
__global__ __launch_bounds__(256) void scatterpos_kernel(
    const int* __restrict__ counts, const int* __restrict__ bsum,
    int* __restrict__ offsets, int* __restrict__ cursor)
{
    __shared__ int sdata[256];
    const int t = threadIdx.x;
    const int base = blockIdx.x * SCAN_CHUNK;
    int c[4];
#pragma unroll
    for (int k = 0; k < 4; ++k) {
        const int i = base + t * 4 + k;
        c[k] = (i < NP) ? counts[i] : 0;
    }
    const int l0 = c[0];
    const int l1 = l0 + c[1];
    const int l2 = l1 + c[2];
    const int l3 = l2 + c[3];
    sdata[t] = l3;
    __syncthreads();
    // Hillis-Steele inclusive scan over 256 thread totals
    for (int off = 1; off < 256; off <<= 1) {
        int v = (t >= off) ? sdata[t - off] : 0;
        __syncthreads();
        sdata[t] += v;
        __syncthreads();
    }
    const int tbase = bsum[blockIdx.x] + sdata[t] - l3;  // exclusive base for this thread
    const int ex[4] = {0, l0, l1, l2};
#pragma unroll
    for (int k = 0; k < 4; ++k) {
        const int i = base + t * 4 + k;
        if (i < NP) {
            const int o = tbase + ex[k];
            offsets[i] = o;
            cursor[i]  = o;
        }
    }
}

// fill: sorted_src[pos++] = src for each edge, bucketed by dst
__global__ __launch_bounds__(256) void fill_kernel(
    const int* __restrict__ ei, int* __restrict__ cursor,
    int* __restrict__ sorted_src)
{
    const int e = blockIdx.x * 256 + threadIdx.x;
    if (e < NE) {
        const int d = ei[NE + e];
        const int pos = atomicAdd(&cursor[d], 1);
        sorted_src[pos] = ei[e];
    }
}

// ---------------------------------------------------------------------------
// Gather segment-sum: agg[row] = sum over CSR range of g[src]
// one block (128 threads = channels) per patient row
// ---------------------------------------------------------------------------
__global__ __launch_bounds__(128) void agg_kernel(
    const int* __restrict__ offsets, const int* __restrict__ sorted_src,
    const float* __restrict__ g, float* __restrict__ agg)
{
    const int row = blockIdx.x;
    const int j = threadIdx.x;
    const int start = offsets[row];
    const int end   = offsets[row + 1];
    float s0 = 0.f, s1 = 0.f;
    int e = start;
    for (; e + 1 < end; e += 2) {
        const int a = sorted_src[e];
        const int b = sorted_src[e + 1];
        s0 += g[(size_t)a * HD + j];
        s1 += g[(size_t)b * HD + j];
    }
    if (e < end) s0 += g[(size_t)sorted_src[e] * HD + j];
    agg[(size_t)row * HD + j] = s0 + s1;
}

// ---------------------------------------------------------------------------
// Fused patient pipeline (unchanged from round 1)
// ---------------------------------------------------------------------------
__global__ __launch_bounds__(128) void patient_fused_kernel(
    const float* __restrict__ xp,   // [NP, PD]
    const float* __restrict__ agg,  // [NP, HD]
    const float* __restrict__ Wp1, const float* __restrict__ bp1,
    const float* __restrict__ Wp2, const float* __restrict__ bp2,
    const float* __restrict__ W1l, const float* __restrict__ b1l,
    const float* __restrict__ W1r,
    const float* __restrict__ W2l, const float* __restrict__ b2l,
    const float* __restrict__ W2r,
    const float* __restrict__ Wfc, const float* __restrict__ bfc,
    float* __restrict__ out)        // [NP, OD]
{
    __shared__ __align__(16) float A[RD * HD];
    __shared__ __align__(16) float B[RD * HD];
    const int j = threadIdx.x;
    const int row0 = blockIdx.x * RD;

    float acc[RD];

    // ---- patient MLP layer 1: relu(xp @ Wp1 + bp1) -> A
    {
        const float b = bp1[j];
#pragma unroll
        for (int r = 0; r < RD; ++r) acc[r] = b;
        for (int k = 0; k < PD; k += 4) {
            const float w0 = Wp1[(k + 0) * HD + j];
            const float w1 = Wp1[(k + 1) * HD + j];
            const float w2 = Wp1[(k + 2) * HD + j];
            const float w3 = Wp1[(k + 3) * HD + j];
#pragma unroll
            for (int r = 0; r < RD; ++r) {
                const float* xr = xp + (size_t)(row0 + r) * PD + k;
                acc[r] = fmaf(xr[0], w0, acc[r]);
                acc[r] = fmaf(xr[1], w1, acc[r]);
                acc[r] = fmaf(xr[2], w2, acc[r]);
                acc[r] = fmaf(xr[3], w3, acc[r]);
            }
        }
#pragma unroll
        for (int r = 0; r < RD; ++r) A[r * HD + j] = fmaxf(acc[r], 0.f);
        __syncthreads();
    }

    // ---- patient MLP layer 2: A @ Wp2 + bp2 (no relu) -> B
    {
        const float b = bp2[j];
#pragma unroll
        for (int r = 0; r < RD; ++r) acc[r] = b;
        for (int k = 0; k < HD; k += 4) {
            const float w0 = Wp2[(k + 0) * HD + j];
            const float w1 = Wp2[(k + 1) * HD + j];
            const float w2 = Wp2[(k + 2) * HD + j];
            const float w3 = Wp2[(k + 3) * HD + j];
#pragma unroll
            for (int r = 0; r < RD; ++r) {
                const float4 a4 = *(const float4*)&A[r * HD + k];
                acc[r] = fmaf(a4.x, w0, acc[r]);
                acc[r] = fmaf(a4.y, w1, acc[r]);
                acc[r] = fmaf(a4.z, w2, acc[r]);
                acc[r] = fmaf(a4.w, w3, acc[r]);
            }
        }
        __syncthreads();  // everyone done reading A
#pragma unroll
        for (int r = 0; r < RD; ++r) B[r * HD + j] = acc[r];
        __syncthreads();
    }

    // ---- SAGE layer 1: relu(agg @ W1l + b1l + B @ W1r) -> A
    {
        const float b = b1l[j];
#pragma unroll
        for (int r = 0; r < RD; ++r) acc[r] = b;
        for (int k = 0; k < HD; k += 4) {
            const float wl0 = W1l[(k + 0) * HD + j];
            const float wl1 = W1l[(k + 1) * HD + j];
            const float wl2 = W1l[(k + 2) * HD + j];
            const float wl3 = W1l[(k + 3) * HD + j];
            const float wr0 = W1r[(k + 0) * HD + j];
            const float wr1 = W1r[(k + 1) * HD + j];
            const float wr2 = W1r[(k + 2) * HD + j];
            const float wr3 = W1r[(k + 3) * HD + j];
#pragma unroll
            for (int r = 0; r < RD; ++r) {
                const float* ar = agg + (size_t)(row0 + r) * HD + k;
                const float4 p4 = *(const float4*)&B[r * HD + k];
                acc[r] = fmaf(ar[0], wl0, acc[r]);
                acc[r] = fmaf(p4.x, wr0, acc[r]);
                acc[r] = fmaf(ar[1], wl1, acc[r]);
                acc[r] = fmaf(p4.y, wr1, acc[r]);
                acc[r] = fmaf(ar[2], wl2, acc[r]);
                acc[r] = fmaf(p4.z, wr2, acc[r]);
                acc[r] = fmaf(ar[3], wl3, acc[r]);
                acc[r] = fmaf(p4.w, wr3, acc[r]);
            }
        }
        __syncthreads();  // everyone done reading B
#pragma unroll
        for (int r = 0; r < RD; ++r) A[r * HD + j] = fmaxf(acc[r], 0.f);
        __syncthreads();
    }

    // ---- SAGE layer 2: relu(agg @ W2l + b2l + A @ W2r) -> B
    {
        const float b = b2l[j];
#pragma unroll
        for (int r = 0; r < RD; ++r) acc[r] = b;
        for (int k = 0; k < HD; k += 4) {
            const float wl0 = W2l[(k + 0) * HD + j];
            const float wl1 = W2l[(k + 1) * HD + j];
            const float wl2 = W2l[(k + 2) * HD + j];
            const float wl3 = W2l[(k + 3) * HD + j];
            const float wr0 = W2r[(k + 0) * HD + j];
            const float wr1 = W2r[(k + 1) * HD + j];
            const float wr2 = W2r[(k + 2) * HD + j];
            const float wr3 = W2r[(k + 3) * HD + j];
#pragma unroll
            for (int r = 0; r < RD; ++r) {
                const float* ar = agg + (size_t)(row0 + r) * HD + k;
                const float4 h4 = *(const float4*)&A[r * HD + k];
                acc[r] = fmaf(ar[0], wl0, acc[r]);
                acc[r] = fmaf(h4.x, wr0, acc[r]);
                acc[r] = fmaf(ar[1], wl1, acc[r]);
                acc[r] = fmaf(h4.y, wr1, acc[r]);
                acc[r] = fmaf(ar[2], wl2, acc[r]);
                acc[r] = fmaf(h4.z, wr2, acc[r]);
                acc[r] = fmaf(ar[3], wl3, acc[r]);
                acc[r] = fmaf(h4.w, wr3, acc[r]);
            }
        }
        __syncthreads();  // everyone done reading A
#pragma unroll
        for (int r = 0; r < RD; ++r) B[r * HD + j] = fmaxf(acc[r], 0.f);
        __syncthreads();
    }

    // ---- fc: out = B @ Wfc + bfc  (threads 0..RD*OD-1, one (row, out) each)
    if (j < RD * OD) {
        const int r = j >> 3;
        const int o = j & 7;
        float s = bfc[o];
        for (int k = 0; k < HD; k += 4) {
            const float4 h4 = *(const float4*)&B[r * HD + k];
            s = fmaf(h4.x, Wfc[(k + 0) * OD + o], s);
            s = fmaf(h4.y, Wfc[(k + 1) * OD + o], s);
            s = fmaf(h4.z, Wfc[(k + 2) * OD + o], s);
            s = fmaf(h4.w, Wfc[(k + 3) * OD + o], s);
        }
        out[(size_t)(row0 + r) * OD + o] = s;
    }
}

// ---------------------------------------------------------------------------
extern "C" void kernel_launch(void* const* d_in, const int* in_sizes, int n_in,
                              void* d_out, int out_size, void* d_ws, size_t ws_size,
                              hipStream_t stream)
{
    const float* xp  = (const float*)d_in[0];
    const float* xg  = (const float*)d_in[1];
    const int*   ei  = (const int*)d_in[2];
    const float* Wp1 = (const float*)d_in[3];
    const float* bp1 = (const float*)d_in[4];
    const float* Wp2 = (const float*)d_in[5];
    const float* bp2 = (const float*)d_in[6];
    const float* Wg1 = (const float*)d_in[7];
    const float* bg1 = (const float*)d_in[8];
    const float* Wg2 = (const float*)d_in[9];
    const float* bg2 = (const float*)d_in[10];
    const float* W1l = (const float*)d_in[11];
    const float* b1l = (const float*)d_in[12];
    const float* W1r = (const float*)d_in[13];
    const float* W2l = (const float*)d_in[14];
    const float* b2l = (const float*)d_in[15];
    const float* W2r = (const float*)d_in[16];
    const float* Wfc = (const float*)d_in[17];
    const float* bfc = (const float*)d_in[18];
    float* out = (float*)d_out;

    // ---- workspace layout (floats/ints) -------------------------------
    // g          : [0, NG*HD)                       = 2,560,000 f  (10.24 MB)
    // agg        : [2,560,000, 8,960,000)           = 6,400,000 f  (25.6 MB)
    // offsets    : 50,001 ints at 8,960,000
    // sorted_src : 640,000 ints at 9,010,004
    // counts / cursor / bsum alias the agg region (dead before agg_kernel runs)
    float* g   = (float*)d_ws;
    float* agg = g + (size_t)NG * HD;
    int* offsets    = (int*)(g + 8960000);
    int* sorted_src = (int*)(g + 9010004);
    int* counts = (int*)agg;                 // 50,000 ints
    int* cursor = (int*)(agg + 65536);       // 50,000 ints
    int* bsum   = (int*)(agg + 131072);      // 49 ints

    // 1) gene MLP
    gene_mlp_kernel<<<NG / RD, 128, 0, stream>>>(xg, Wg1, bg1, Wg2, bg2, g);

    // 2) CSR build: histogram -> scan -> fill
    hipMemsetAsync(counts, 0, NP * sizeof(int), stream);
    hist_kernel<<<(NE + 255) / 256, 256, 0, stream>>>(ei, counts);
    blocksum_kernel<<<SCAN_NB, 256, 0, stream>>>(counts, bsum);
    scanbsums_kernel<<<1, 64, 0, stream>>>(bsum, offsets);
    scatterpos_kernel<<<SCAN_NB, 256, 0, stream>>>(counts, bsum, offsets, cursor);
    fill_kernel<<<(NE + 255) / 256, 256, 0, stream>>>(ei, cursor, sorted_src);

    // 3) gather segment-sum (replaces the 82M-fp32-atomic scatter)
    agg_kernel<<<NP, 128, 0, stream>>>(offsets, sorted_src, g, agg);

    // 4) fused patient MLP + SAGE1 + SAGE2 + fc
    patient_fused_kernel<<<NP / RD, 128, 0, stream>>>(
        xp, agg, Wp1, bp1, Wp2, bp2, W1l, b1l, W1r, W2l, b2l, W2r, Wfc, bfc, out);
}